// Round 10
// baseline (455.044 us; speedup 1.0000x reference)
//
#include <hip/hip_runtime.h>
#include <hip/hip_bf16.h>

// hexagdly conv2d as implicit GEMM with bf16 MFMA.
// out[b,co,h,w] = bias[co]
//   + sum_ci sum_{t=0..2} x[b,ci,h-1+t,w]   * k0[co,ci,t]
//   + (w even) sum_ci sum_{kh,kw} x[b,ci,h-1+kh,w-1+2kw] * k1[co,ci,kh,kw]
//   + (w odd)  sum_ci sum_{kh,kw} x[b,ci,h+kh,  w-1+2kw] * k1[co,ci,kh,kw]
//
// R10 = R5 (98.4us, passing) + 2 tiles per block (grid 1024): tile 1's
// store burst drains under tile 2's staging/compute. Weight pipeline,
// counted vmcnt, x-staging, LDS-bounce epilogue all R5-verbatim.

#define CIN  64
#define COUT 128
#define HH   256
#define WW   256
#define TH   8
#define TW   32
#define XR   10   // TH + 2 halo rows
#define XC   34   // TW + 2 halo cols

typedef __attribute__((ext_vector_type(8))) short short8;
typedef __attribute__((ext_vector_type(4))) float f32x4;

static __device__ __forceinline__ unsigned short f2bf(float v) {
    __hip_bfloat16 h = __float2bfloat16(v);
    return __builtin_bit_cast(unsigned short, h);
}

typedef __attribute__((address_space(1))) const unsigned int asg_u32;
typedef __attribute__((address_space(3))) unsigned int asl_u32;
static __device__ __forceinline__ void gl2lds16(const void* g, void* l) {
    __builtin_amdgcn_global_load_lds((asg_u32*)g, (asl_u32*)l, 16, 0, 0);
}

#define XS_BYTES   (XR * XC * CIN * 2)               // 43520
#define WTB_OFF    XS_BYTES
#define SMEM_BYTES (XS_BYTES + 2 * COUT * CIN * 2)   // 43520 + 32768 = 76288
#define OT_STRIDE  33                                // padded w row (floats)
#define WTAP       (COUT * CIN)                      // halfwords per tap = 8192

// ---------- pre-kernel: k0/k1 -> bf16 [tap][co][ci], pre-swizzled ----------
__global__ __launch_bounds__(512)
void prep_weights(const float* __restrict__ k0, const float* __restrict__ k1,
                  unsigned short* __restrict__ wsw)
{
    const int idx = blockIdx.x * 512 + threadIdx.x;   // 0..7167
    if (idx >= 7 * COUT * 8) return;
    const int t   = idx >> 10;         // tap 0..6
    const int co  = (idx >> 3) & 127;
    const int ci0 = (idx & 7) * 8;
    short8 wv;
    #pragma unroll
    for (int j = 0; j < 8; ++j) {
        const int ci = ci0 + j;
        float v = (t < 3) ? k0[(co * CIN + ci) * 3 + t]
                          : k1[(co * CIN + ci) * 4 + (t - 3)];
        wv[j] = (short)f2bf(v);
    }
    const int e = (co * CIN + ci0) ^ ((co & 7) * 8);
    *(short8*)&wsw[t * WTAP + e] = wv;
}

__global__ __launch_bounds__(512, 4)
void hexconv_mfma(const float* __restrict__ x,
                  const unsigned short* __restrict__ wsw,
                  const float* __restrict__ bias,
                  float* __restrict__ out)
{
    __shared__ alignas(16) char smem[SMEM_BYTES];
    __shared__ float bias_lds[COUT];
    unsigned short* xs  = (unsigned short*)smem;
    unsigned short* wtb = (unsigned short*)(smem + WTB_OFF);
    float*          ot  = (float*)smem;           // epilogue bounce buffer

    const int tid  = threadIdx.x;
    const int lane = tid & 63;
    const int wid  = tid >> 6;       // 8 waves

    // XCD-aware swizzle: nwg = 1024 = 8 XCD x 128; each XCD owns one batch image
    const int wg  = (blockIdx.x & 7) * 128 + (blockIdx.x >> 3);
    const int b   = wg >> 7;          // batch 0..7
    const int by  = (wg >> 2) & 31;   // h tile 0..31
    const int bxp = wg & 3;           // w tile-pair 0..3

    const int h0     = by * TH;
    const int w0base = bxp * (2 * TW);   // even

    // ---- weight staging via async global->LDS (linear dest, pre-swizzled src) ----
    auto stage_tap = [&](int t, int buf) {
        const unsigned short* s0 = wsw + t * WTAP + wid * 1024;
        unsigned short* d0 = wtb + buf * WTAP + wid * 1024;
        gl2lds16(s0 + lane * 8, d0);
        gl2lds16(s0 + 512 + lane * 8, d0 + 512);
    };

    if (tid < COUT) bias_lds[tid] = bias[tid];

    // wave/fragment constants (w0-independent)
    const int wm   = wid & 1;        // co block of 64
    const int wn   = wid >> 1;       // 2 h-rows of 32 cols each
    const int c15  = lane & 15;
    const int q8   = (lane >> 4) * 8;
    const int par  = lane & 1;       // parity of output column (w0 even)
    const int aBase = (wm * 64 + c15) * CIN + q8;
    const int swzA  = (c15 & 7) * 8;

    for (int t2 = 0; t2 < 2; ++t2) {
        const int w0 = w0base + t2 * TW;

        // tap-0 weights -> buffer 0 (for t2=1 this follows the tile-end barrier,
        // so the ot region overlapping wtb is no longer being read)
        stage_tap(0, 0);

        // ---------- stage x tile: fp32 -> bf16 (vectorized), ci-contiguous ----------
        {
            const float* xb = x + (size_t)b * CIN * HH * WW;
            const int cg = tid & 7;              // col group: gw = w0 + 4*cg + k
            const int u0 = tid >> 3;             // unit: (row, ci-pair)
            #pragma unroll
            for (int it = 0; it < 5; ++it) {
                const int u   = u0 + it * 64;    // 0..319
                const int row = u >> 5;          // 0..9
                const int ci  = (u & 31) * 2;
                const int gh  = h0 - 1 + row;
                f32x4 a = (f32x4)0.0f, c = (f32x4)0.0f;
                if ((unsigned)gh < HH) {
                    const float* pb = xb + ((size_t)ci * HH + gh) * WW + w0 + 4 * cg;
                    a = *(const f32x4*)pb;
                    c = *(const f32x4*)(pb + HH * WW);
                }
                #pragma unroll
                for (int k = 0; k < 4; ++k) {
                    const int col = 4 * cg + 1 + k;
                    unsigned int pk = (unsigned int)f2bf(a[k]) | ((unsigned int)f2bf(c[k]) << 16);
                    const int e = ((row * XC + col) * CIN + ci) ^ ((col & 7) * 8);
                    *(unsigned int*)&xs[e] = pk;
                }
            }
            // halo cols: col 0 (gw = w0-1) and col 33 (gw = w0+32)
            for (int i = tid; i < 2 * XR * CIN; i += 512) {
                const int side = (i >= XR * CIN) ? 1 : 0;
                const int rem  = i - side * XR * CIN;
                const int row  = rem >> 6;
                const int ci   = rem & 63;
                const int col  = side ? (XC - 1) : 0;
                const int gh   = h0 - 1 + row;
                const int gw   = side ? (w0 + TW) : (w0 - 1);
                float v = 0.f;
                if ((unsigned)gh < HH && (unsigned)gw < WW)
                    v = xb[((size_t)ci * HH + gh) * WW + gw];
                const int e = ((row * XC + col) * CIN + ci) ^ ((col & 7) * 8);
                xs[e] = f2bf(v);
            }
        }

        __syncthreads();   // full drain: tap-0 weights + x tile ready

        f32x4 acc[4][4];
        #pragma unroll
        for (int mi = 0; mi < 4; ++mi)
            #pragma unroll
            for (int ni = 0; ni < 4; ++ni)
                acc[mi][ni] = (f32x4)0.0f;

        #pragma unroll
        for (int tap = 0; tap < 7; ++tap) {
            // issue next tap's weight loads; they stay in flight under this tap's MFMAs
            if (tap < 6) {
                stage_tap(tap + 1, (tap + 1) & 1);
                asm volatile("s_waitcnt vmcnt(2)" ::: "memory");   // tap t's loads landed
            } else {
                asm volatile("s_waitcnt vmcnt(0)" ::: "memory");
            }
            __builtin_amdgcn_s_barrier();          // all waves' tap-t weights visible
            __builtin_amdgcn_sched_barrier(0);

            const unsigned short* wc = wtb + (tap & 1) * WTAP;

            int R0, P, C0;
            if (tap < 3) { R0 = tap; P = 0; C0 = 1; }                   // vertical 3x1
            else { R0 = (tap - 3) >> 1; P = 1; C0 = ((tap - 3) & 1) * 2; } // hex 2x2
            const int colb  = c15 + C0;
            const int swzB  = (colb & 7) * 8;
            const int bBase = ((wn * 2 + R0 + P * par) * XC + colb) * CIN + q8;

            #pragma unroll
            for (int ci0 = 0; ci0 < CIN; ci0 += 32) {
                short8 af[4];
                #pragma unroll
                for (int mi = 0; mi < 4; ++mi)
                    af[mi] = *(const short8*)&wc[(aBase + mi * 16 * CIN + ci0) ^ swzA];
                #pragma unroll
                for (int ni = 0; ni < 4; ++ni) {
                    const int hr = ni >> 1, chalf = ni & 1;
                    const int e = (bBase + hr * (XC * CIN) + chalf * (16 * CIN) + ci0) ^ swzB;
                    short8 bf = *(const short8*)&xs[e];
                    #pragma unroll
                    for (int mi = 0; mi < 4; ++mi)
                        acc[mi][ni] = __builtin_amdgcn_mfma_f32_16x16x32_bf16(
                            af[mi], bf, acc[mi][ni], 0, 0, 0);
                }
            }

            asm volatile("s_waitcnt lgkmcnt(0)" ::: "memory");
            __builtin_amdgcn_sched_barrier(0);
            __builtin_amdgcn_s_barrier();
        }

        // ---------- epilogue: LDS bounce for fully-coalesced 128B row stores ----------
        // C/D layout (16x16): col = lane&15, row = (lane>>4)*4 + reg
        #pragma unroll
        for (int p = 0; p < 2; ++p) {
            if (wm == p) {
                #pragma unroll
                for (int mi = 0; mi < 4; ++mi) {
                    #pragma unroll
                    for (int ni = 0; ni < 4; ++ni) {
                        const int hh   = wn * 2 + (ni >> 1);
                        const int wloc = (ni & 1) * 16 + c15;
                        #pragma unroll
                        for (int r = 0; r < 4; ++r) {
                            const int col = mi * 16 + (lane >> 4) * 4 + r;   // local co
                            ot[(col * TH + hh) * OT_STRIDE + wloc] =
                                acc[mi][ni][r] + bias_lds[p * 64 + col];
                        }
                    }
                }
            }
            asm volatile("s_waitcnt lgkmcnt(0)" ::: "memory");
            __builtin_amdgcn_sched_barrier(0);
            __builtin_amdgcn_s_barrier();
            // 512 threads x 8 iters = 4096 float4 = 64co x 8h x 32w
            #pragma unroll
            for (int it = 0; it < 8; ++it) {
                const int col = it * 8 + (tid >> 6);     // local co
                const int hh  = (tid >> 3) & 7;
                const int w4  = (tid & 7) * 4;
                const float* src = &ot[(col * TH + hh) * OT_STRIDE + w4];
                f32x4 v = { src[0], src[1], src[2], src[3] };
                __builtin_nontemporal_store(v,
                    (f32x4*)&out[(((size_t)b * COUT + p * 64 + col) * HH + h0 + hh) * WW + w0 + w4]);
            }
            // barrier before ot is overwritten (p=1 pass, or next tile's staging)
            asm volatile("s_waitcnt lgkmcnt(0)" ::: "memory");
            __builtin_amdgcn_sched_barrier(0);
            __builtin_amdgcn_s_barrier();
        }
    }
}

extern "C" void kernel_launch(void* const* d_in, const int* in_sizes, int n_in,
                              void* d_out, int out_size, void* d_ws, size_t ws_size,
                              hipStream_t stream) {
    const float* x    = (const float*)d_in[0];
    const float* k0   = (const float*)d_in[1];
    const float* k1   = (const float*)d_in[2];
    const float* bias = (const float*)d_in[3];
    float* out        = (float*)d_out;
    unsigned short* wsw = (unsigned short*)d_ws;   // 7*128*64*2 = 114688 B

    prep_weights<<<dim3(14, 1, 1), 512, 0, stream>>>(k0, k1, wsw);
    hexconv_mfma<<<dim3(1024, 1, 1), 512, 0, stream>>>(x, wsw, bias, out);
}

// Round 11
// 112.250 us; speedup vs baseline: 4.0538x; 4.0538x over previous
//
#include <hip/hip_runtime.h>
#include <hip/hip_bf16.h>

// hexagdly conv2d as implicit GEMM with bf16 MFMA.
// out[b,co,h,w] = bias[co]
//   + sum_ci sum_{t=0..2} x[b,ci,h-1+t,w]   * k0[co,ci,t]
//   + (w even) sum_ci sum_{kh,kw} x[b,ci,h-1+kh,w-1+2kw] * k1[co,ci,kh,kw]
//   + (w odd)  sum_ci sum_{kh,kw} x[b,ci,h+kh,  w-1+2kw] * k1[co,ci,kh,kw]
//
// R11 = R5 (98.4us) + (a) single barrier per tap: stage(t+1) moved AFTER
// barrier(t) — all waves past barrier(t) have consumed tap t-1 reads
// (in-order issue), so buf[(t+1)&1] is dead and safe to overwrite; and
// (b) anti-phase spin (~6us) for initial second-resident cohort
// (blockIdx 256..511) to de-collide the per-CU store bursts.

#define CIN  64
#define COUT 128
#define HH   256
#define WW   256
#define TH   8
#define TW   32
#define XR   10   // TH + 2 halo rows
#define XC   34   // TW + 2 halo cols

typedef __attribute__((ext_vector_type(8))) short short8;
typedef __attribute__((ext_vector_type(4))) float f32x4;

static __device__ __forceinline__ unsigned short f2bf(float v) {
    __hip_bfloat16 h = __float2bfloat16(v);
    return __builtin_bit_cast(unsigned short, h);
}

typedef __attribute__((address_space(1))) const unsigned int asg_u32;
typedef __attribute__((address_space(3))) unsigned int asl_u32;
static __device__ __forceinline__ void gl2lds16(const void* g, void* l) {
    __builtin_amdgcn_global_load_lds((asg_u32*)g, (asl_u32*)l, 16, 0, 0);
}

#define XS_BYTES   (XR * XC * CIN * 2)               // 43520
#define WTB_OFF    XS_BYTES
#define SMEM_BYTES (XS_BYTES + 2 * COUT * CIN * 2)   // 43520 + 32768 = 76288
#define OT_STRIDE  33                                // padded w row (floats)
#define WTAP       (COUT * CIN)                      // halfwords per tap = 8192

// ---------- pre-kernel: k0/k1 -> bf16 [tap][co][ci], pre-swizzled ----------
__global__ __launch_bounds__(512)
void prep_weights(const float* __restrict__ k0, const float* __restrict__ k1,
                  unsigned short* __restrict__ wsw)
{
    const int idx = blockIdx.x * 512 + threadIdx.x;   // 0..7167
    if (idx >= 7 * COUT * 8) return;
    const int t   = idx >> 10;         // tap 0..6
    const int co  = (idx >> 3) & 127;
    const int ci0 = (idx & 7) * 8;
    short8 wv;
    #pragma unroll
    for (int j = 0; j < 8; ++j) {
        const int ci = ci0 + j;
        float v = (t < 3) ? k0[(co * CIN + ci) * 3 + t]
                          : k1[(co * CIN + ci) * 4 + (t - 3)];
        wv[j] = (short)f2bf(v);
    }
    const int e = (co * CIN + ci0) ^ ((co & 7) * 8);
    *(short8*)&wsw[t * WTAP + e] = wv;
}

__global__ __launch_bounds__(512, 4)
void hexconv_mfma(const float* __restrict__ x,
                  const unsigned short* __restrict__ wsw,
                  const float* __restrict__ bias,
                  float* __restrict__ out)
{
    __shared__ alignas(16) char smem[SMEM_BYTES];
    __shared__ float bias_lds[COUT];
    unsigned short* xs  = (unsigned short*)smem;
    unsigned short* wtb = (unsigned short*)(smem + WTB_OFF);
    float*          ot  = (float*)smem;           // epilogue bounce buffer

    const int tid  = threadIdx.x;
    const int lane = tid & 63;
    const int wid  = tid >> 6;       // 8 waves

    // (b) anti-phase: second-resident cohort delays ~6us (half a block period)
    if ((blockIdx.x >> 8) == 1) {
        #pragma unroll 1
        for (int i = 0; i < 1200; ++i) asm volatile("s_nop 7");
    }

    // XCD-aware swizzle: nwg = 2048 = 8 XCD x 256; each XCD gets one batch image
    const int wg = (blockIdx.x & 7) * 256 + (blockIdx.x >> 3);
    const int bx = wg & 7;            // w tile 0..7
    const int by = (wg >> 3) & 31;    // h tile 0..31
    const int b  = wg >> 8;           // batch 0..7

    const int h0 = by * TH;
    const int w0 = bx * TW;           // even

    // ---- weight staging via async global->LDS (linear dest, pre-swizzled src) ----
    // wave wid owns halfwords [wid*1024, wid*1024+1024) of the 8192-halfword tap
    auto stage_tap = [&](int t, int buf) {
        const unsigned short* s0 = wsw + t * WTAP + wid * 1024;
        unsigned short* d0 = wtb + buf * WTAP + wid * 1024;
        gl2lds16(s0 + lane * 8, d0);
        gl2lds16(s0 + 512 + lane * 8, d0 + 512);
    };

    stage_tap(0, 0);   // tap 0 -> buffer 0, overlaps x staging

    if (tid < COUT) bias_lds[tid] = bias[tid];

    // ---------- stage x tile: fp32 -> bf16 (vectorized), ci-contiguous ----------
    {
        const float* xb = x + (size_t)b * CIN * HH * WW;
        // interior cols 1..32 (gw = w0..w0+31): float4 over 4 w, 2 ci per unit
        const int cg = tid & 7;              // col group: gw = w0 + 4*cg + k
        const int u0 = tid >> 3;             // unit: (row, ci-pair)
        #pragma unroll
        for (int it = 0; it < 5; ++it) {
            const int u   = u0 + it * 64;    // 0..319
            const int row = u >> 5;          // 0..9
            const int ci  = (u & 31) * 2;
            const int gh  = h0 - 1 + row;
            f32x4 a = (f32x4)0.0f, c = (f32x4)0.0f;
            if ((unsigned)gh < HH) {
                const float* pb = xb + ((size_t)ci * HH + gh) * WW + w0 + 4 * cg;
                a = *(const f32x4*)pb;
                c = *(const f32x4*)(pb + HH * WW);
            }
            #pragma unroll
            for (int k = 0; k < 4; ++k) {
                const int col = 4 * cg + 1 + k;
                unsigned int pk = (unsigned int)f2bf(a[k]) | ((unsigned int)f2bf(c[k]) << 16);
                const int e = ((row * XC + col) * CIN + ci) ^ ((col & 7) * 8);
                *(unsigned int*)&xs[e] = pk;
            }
        }
        // halo cols: col 0 (gw = w0-1) and col 33 (gw = w0+32)
        for (int i = tid; i < 2 * XR * CIN; i += 512) {
            const int side = (i >= XR * CIN) ? 1 : 0;
            const int rem  = i - side * XR * CIN;
            const int row  = rem >> 6;
            const int ci   = rem & 63;
            const int col  = side ? (XC - 1) : 0;
            const int gh   = h0 - 1 + row;
            const int gw   = side ? (w0 + TW) : (w0 - 1);
            float v = 0.f;
            if ((unsigned)gh < HH && (unsigned)gw < WW)
                v = xb[((size_t)ci * HH + gh) * WW + gw];
            const int e = ((row * XC + col) * CIN + ci) ^ ((col & 7) * 8);
            xs[e] = f2bf(v);
        }
    }

    __syncthreads();   // full drain: tap-0 weights + x tile ready

    // ---------- compute: wave tiling ----------
    const int wm   = wid & 1;        // co block of 64
    const int wn   = wid >> 1;       // 2 h-rows of 32 cols each
    const int c15  = lane & 15;
    const int q8   = (lane >> 4) * 8;
    const int par  = lane & 1;       // parity of output column (w0 even)

    const int aBase = (wm * 64 + c15) * CIN + q8;
    const int swzA  = (c15 & 7) * 8;

    f32x4 acc[4][4];
    #pragma unroll
    for (int mi = 0; mi < 4; ++mi)
        #pragma unroll
        for (int ni = 0; ni < 4; ++ni)
            acc[mi][ni] = (f32x4)0.0f;

    #pragma unroll
    for (int tap = 0; tap < 7; ++tap) {
        if (tap > 0) {
            // stage(tap) was issued after barrier(tap-1); drain it, then sync.
            asm volatile("s_waitcnt vmcnt(0)" ::: "memory");
            __builtin_amdgcn_s_barrier();
            __builtin_amdgcn_sched_barrier(0);
        }
        // safe to overwrite buf[(tap+1)&1]: every wave past barrier(tap) has
        // consumed its tap-1 reads (in-order issue + operand waits).
        if (tap < 6) stage_tap(tap + 1, (tap + 1) & 1);

        const unsigned short* wc = wtb + (tap & 1) * WTAP;

        // B-operand address parameters for this tap
        int R0, P, C0;
        if (tap < 3) { R0 = tap; P = 0; C0 = 1; }                   // vertical 3x1
        else { R0 = (tap - 3) >> 1; P = 1; C0 = ((tap - 3) & 1) * 2; } // hex 2x2
        const int colb  = c15 + C0;                 // + chalf*16 later (&7 invariant)
        const int swzB  = (colb & 7) * 8;
        const int bBase = ((wn * 2 + R0 + P * par) * XC + colb) * CIN + q8;

        #pragma unroll
        for (int ci0 = 0; ci0 < CIN; ci0 += 32) {
            short8 af[4];
            #pragma unroll
            for (int mi = 0; mi < 4; ++mi)
                af[mi] = *(const short8*)&wc[(aBase + mi * 16 * CIN + ci0) ^ swzA];
            #pragma unroll
            for (int ni = 0; ni < 4; ++ni) {
                const int hr = ni >> 1, chalf = ni & 1;
                const int e = (bBase + hr * (XC * CIN) + chalf * (16 * CIN) + ci0) ^ swzB;
                short8 bf = *(const short8*)&xs[e];
                #pragma unroll
                for (int mi = 0; mi < 4; ++mi)
                    acc[mi][ni] = __builtin_amdgcn_mfma_f32_16x16x32_bf16(
                        af[mi], bf, acc[mi][ni], 0, 0, 0);
            }
        }
    }

    // close the tap loop: all xs/wtb reads done before ot (aliasing) is written
    asm volatile("s_waitcnt lgkmcnt(0)" ::: "memory");
    __builtin_amdgcn_sched_barrier(0);
    __builtin_amdgcn_s_barrier();

    // ---------- epilogue: LDS bounce for fully-coalesced 128B row stores ----------
    // C/D layout (16x16): col = lane&15, row = (lane>>4)*4 + reg
    #pragma unroll
    for (int p = 0; p < 2; ++p) {
        if (wm == p) {
            #pragma unroll
            for (int mi = 0; mi < 4; ++mi) {
                #pragma unroll
                for (int ni = 0; ni < 4; ++ni) {
                    const int hh   = wn * 2 + (ni >> 1);
                    const int wloc = (ni & 1) * 16 + c15;
                    #pragma unroll
                    for (int r = 0; r < 4; ++r) {
                        const int col = mi * 16 + (lane >> 4) * 4 + r;   // local co 0..63
                        ot[(col * TH + hh) * OT_STRIDE + wloc] =
                            acc[mi][ni][r] + bias_lds[p * 64 + col];
                    }
                }
            }
        }
        asm volatile("s_waitcnt lgkmcnt(0)" ::: "memory");
        __builtin_amdgcn_sched_barrier(0);
        __builtin_amdgcn_s_barrier();
        // 512 threads x 8 iters = 4096 float4 = 64co x 8h x 32w
        #pragma unroll
        for (int it = 0; it < 8; ++it) {
            const int col = it * 8 + (tid >> 6);     // local co
            const int hh  = (tid >> 3) & 7;
            const int w4  = (tid & 7) * 4;
            const float* src = &ot[(col * TH + hh) * OT_STRIDE + w4];
            f32x4 v = { src[0], src[1], src[2], src[3] };
            __builtin_nontemporal_store(v,
                (f32x4*)&out[(((size_t)b * COUT + p * 64 + col) * HH + h0 + hh) * WW + w0 + w4]);
        }
        if (p == 0) {
            asm volatile("s_waitcnt lgkmcnt(0)" ::: "memory");
            __builtin_amdgcn_sched_barrier(0);
            __builtin_amdgcn_s_barrier();     // ot reads done before p=1 overwrites
        }
    }
}

extern "C" void kernel_launch(void* const* d_in, const int* in_sizes, int n_in,
                              void* d_out, int out_size, void* d_ws, size_t ws_size,
                              hipStream_t stream) {
    const float* x    = (const float*)d_in[0];
    const float* k0   = (const float*)d_in[1];
    const float* k1   = (const float*)d_in[2];
    const float* bias = (const float*)d_in[3];
    float* out        = (float*)d_out;
    unsigned short* wsw = (unsigned short*)d_ws;   // 7*128*64*2 = 114688 B

    prep_weights<<<dim3(14, 1, 1), 512, 0, stream>>>(k0, k1, wsw);
    hexconv_mfma<<<dim3(2048, 1, 1), 512, 0, stream>>>(x, wsw, bias, out);
}

// Round 12
// 101.404 us; speedup vs baseline: 4.4875x; 1.1070x over previous
//
#include <hip/hip_runtime.h>
#include <hip/hip_bf16.h>

// hexagdly conv2d as implicit GEMM with bf16 MFMA.
// out[b,co,h,w] = bias[co]
//   + sum_ci sum_{t=0..2} x[b,ci,h-1+t,w]   * k0[co,ci,t]
//   + (w even) sum_ci sum_{kh,kw} x[b,ci,h-1+kh,w-1+2kw] * k1[co,ci,kh,kw]
//   + (w odd)  sum_ci sum_{kh,kw} x[b,ci,h+kh,  w-1+2kw] * k1[co,ci,kh,kw]
//
// R12 = R5 pipeline with TH=4 tile + SINGLE-buffered weights: LDS 42.5 KB
// -> 3 blocks/CU (24 waves, 75% occ) so block phases interleave and HBM
// duty rises above R5's 54%. launch_bounds(512,6) caps VGPR at 85.

#define CIN  64
#define COUT 128
#define HH   256
#define WW   256
#define TH   4
#define TW   32
#define XR   6    // TH + 2 halo rows
#define XC   34   // TW + 2 halo cols

typedef __attribute__((ext_vector_type(8))) short short8;
typedef __attribute__((ext_vector_type(4))) float f32x4;

static __device__ __forceinline__ unsigned short f2bf(float v) {
    __hip_bfloat16 h = __float2bfloat16(v);
    return __builtin_bit_cast(unsigned short, h);
}

typedef __attribute__((address_space(1))) const unsigned int asg_u32;
typedef __attribute__((address_space(3))) unsigned int asl_u32;
static __device__ __forceinline__ void gl2lds16(const void* g, void* l) {
    __builtin_amdgcn_global_load_lds((asg_u32*)g, (asl_u32*)l, 16, 0, 0);
}

#define XS_BYTES   (XR * XC * CIN * 2)               // 26112
#define WTB_OFF    XS_BYTES
#define SMEM_BYTES (XS_BYTES + COUT * CIN * 2)       // 26112 + 16384 = 42496
#define OT_STRIDE  33                                // padded w row (floats)
#define WTAP       (COUT * CIN)                      // halfwords per tap = 8192

// ---------- pre-kernel: k0/k1 -> bf16 [tap][co][ci], pre-swizzled ----------
__global__ __launch_bounds__(512)
void prep_weights(const float* __restrict__ k0, const float* __restrict__ k1,
                  unsigned short* __restrict__ wsw)
{
    const int idx = blockIdx.x * 512 + threadIdx.x;   // 0..7167
    if (idx >= 7 * COUT * 8) return;
    const int t   = idx >> 10;         // tap 0..6
    const int co  = (idx >> 3) & 127;
    const int ci0 = (idx & 7) * 8;
    short8 wv;
    #pragma unroll
    for (int j = 0; j < 8; ++j) {
        const int ci = ci0 + j;
        float v = (t < 3) ? k0[(co * CIN + ci) * 3 + t]
                          : k1[(co * CIN + ci) * 4 + (t - 3)];
        wv[j] = (short)f2bf(v);
    }
    const int e = (co * CIN + ci0) ^ ((co & 7) * 8);
    *(short8*)&wsw[t * WTAP + e] = wv;
}

__global__ __launch_bounds__(512, 6)
void hexconv_mfma(const float* __restrict__ x,
                  const unsigned short* __restrict__ wsw,
                  const float* __restrict__ bias,
                  float* __restrict__ out)
{
    __shared__ alignas(16) char smem[SMEM_BYTES];
    __shared__ float bias_lds[COUT];
    unsigned short* xs  = (unsigned short*)smem;
    unsigned short* wtb = (unsigned short*)(smem + WTB_OFF);   // single buffer
    float*          ot  = (float*)smem;           // epilogue bounce buffer

    const int tid  = threadIdx.x;
    const int lane = tid & 63;
    const int wid  = tid >> 6;       // 8 waves

    // XCD-aware swizzle: nwg = 4096 = 8 XCD x 512; each XCD owns one batch image
    const int wg = (blockIdx.x & 7) * 512 + (blockIdx.x >> 3);
    const int bx = wg & 7;            // w tile 0..7
    const int by = (wg >> 3) & 63;    // h tile 0..63
    const int b  = wg >> 9;           // batch 0..7

    const int h0 = by * TH;
    const int w0 = bx * TW;           // even

    // ---- weight staging via async global->LDS (linear dest, pre-swizzled src) ----
    // wave wid owns halfwords [wid*1024, wid*1024+1024) of the 8192-halfword tap
    auto stage_tap = [&](int t) {
        const unsigned short* s0 = wsw + t * WTAP + wid * 1024;
        unsigned short* d0 = wtb + wid * 1024;
        gl2lds16(s0 + lane * 8, d0);
        gl2lds16(s0 + 512 + lane * 8, d0 + 512);
    };

    stage_tap(0);   // tap 0, overlaps x staging (drained by __syncthreads)

    if (tid < COUT) bias_lds[tid] = bias[tid];

    // ---------- stage x tile: fp32 -> bf16 (vectorized), ci-contiguous ----------
    {
        const float* xb = x + (size_t)b * CIN * HH * WW;
        // interior cols 1..32 (gw = w0..w0+31): float4 over 4 w, 2 ci per unit
        const int cg = tid & 7;              // col group: gw = w0 + 4*cg + k
        const int u0 = tid >> 3;             // unit: (row, ci-pair), 0..63
        #pragma unroll
        for (int it = 0; it < 3; ++it) {
            const int u   = u0 + it * 64;    // 0..191 = 6 rows x 32 ci-pairs
            const int row = u >> 5;          // 0..5
            const int ci  = (u & 31) * 2;
            const int gh  = h0 - 1 + row;
            f32x4 a = (f32x4)0.0f, c = (f32x4)0.0f;
            if ((unsigned)gh < HH) {
                const float* pb = xb + ((size_t)ci * HH + gh) * WW + w0 + 4 * cg;
                a = *(const f32x4*)pb;
                c = *(const f32x4*)(pb + HH * WW);
            }
            #pragma unroll
            for (int k = 0; k < 4; ++k) {
                const int col = 4 * cg + 1 + k;
                unsigned int pk = (unsigned int)f2bf(a[k]) | ((unsigned int)f2bf(c[k]) << 16);
                const int e = ((row * XC + col) * CIN + ci) ^ ((col & 7) * 8);
                *(unsigned int*)&xs[e] = pk;
            }
        }
        // halo cols: col 0 (gw = w0-1) and col 33 (gw = w0+32)
        for (int i = tid; i < 2 * XR * CIN; i += 512) {   // 768 elements
            const int side = (i >= XR * CIN) ? 1 : 0;
            const int rem  = i - side * XR * CIN;
            const int row  = rem >> 6;                    // 0..5
            const int ci   = rem & 63;
            const int col  = side ? (XC - 1) : 0;
            const int gh   = h0 - 1 + row;
            const int gw   = side ? (w0 + TW) : (w0 - 1);
            float v = 0.f;
            if ((unsigned)gh < HH && (unsigned)gw < WW)
                v = xb[((size_t)ci * HH + gh) * WW + gw];
            const int e = ((row * XC + col) * CIN + ci) ^ ((col & 7) * 8);
            xs[e] = f2bf(v);
        }
    }

    __syncthreads();   // full drain: tap-0 weights + x tile ready

    // ---------- compute: wave tiling ----------
    const int wm   = wid & 1;        // co block of 64
    const int wn   = wid >> 1;       // output row 0..3
    const int c15  = lane & 15;
    const int q8   = (lane >> 4) * 8;
    const int par  = lane & 1;       // parity of output column (w0 even)

    const int aBase = (wm * 64 + c15) * CIN + q8;
    const int swzA  = (c15 & 7) * 8;

    f32x4 acc[4][2];
    #pragma unroll
    for (int mi = 0; mi < 4; ++mi)
        #pragma unroll
        for (int ni = 0; ni < 2; ++ni)
            acc[mi][ni] = (f32x4)0.0f;

    #pragma unroll
    for (int tap = 0; tap < 7; ++tap) {
        // B-operand address parameters for this tap
        int R0, P, C0;
        if (tap < 3) { R0 = tap; P = 0; C0 = 1; }                   // vertical 3x1
        else { R0 = (tap - 3) >> 1; P = 1; C0 = ((tap - 3) & 1) * 2; } // hex 2x2
        const int colb  = c15 + C0;                 // + ni*16 later (&7 invariant)
        const int swzB  = (colb & 7) * 8;
        const int bBase = ((wn + R0 + P * par) * XC + colb) * CIN + q8;

        #pragma unroll
        for (int ci0 = 0; ci0 < CIN; ci0 += 32) {
            short8 af[4];
            #pragma unroll
            for (int mi = 0; mi < 4; ++mi)
                af[mi] = *(const short8*)&wtb[(aBase + mi * 16 * CIN + ci0) ^ swzA];
            #pragma unroll
            for (int ni = 0; ni < 2; ++ni) {
                const int e = (bBase + ni * (16 * CIN) + ci0) ^ swzB;
                short8 bf = *(const short8*)&xs[e];
                #pragma unroll
                for (int mi = 0; mi < 4; ++mi)
                    acc[mi][ni] = __builtin_amdgcn_mfma_f32_16x16x32_bf16(
                        af[mi], bf, acc[mi][ni], 0, 0, 0);
            }
        }

        if (tap < 6) {
            // all waves done reading wtb -> safe to overwrite
            asm volatile("s_waitcnt lgkmcnt(0)" ::: "memory");
            __builtin_amdgcn_sched_barrier(0);
            __builtin_amdgcn_s_barrier();
            stage_tap(tap + 1);
            asm volatile("s_waitcnt vmcnt(0)" ::: "memory");
            __builtin_amdgcn_sched_barrier(0);
            __builtin_amdgcn_s_barrier();      // new weights visible to all
        }
    }

    // close the tap loop: all xs/wtb reads done before ot (aliasing) is written
    asm volatile("s_waitcnt lgkmcnt(0)" ::: "memory");
    __builtin_amdgcn_sched_barrier(0);
    __builtin_amdgcn_s_barrier();

    // ---------- epilogue: LDS bounce for fully-coalesced 128B row stores ----------
    // C/D layout (16x16): col = lane&15, row = (lane>>4)*4 + reg
    #pragma unroll
    for (int p = 0; p < 2; ++p) {
        if (wm == p) {
            #pragma unroll
            for (int mi = 0; mi < 4; ++mi) {
                #pragma unroll
                for (int ni = 0; ni < 2; ++ni) {
                    const int hh   = wn;
                    const int wloc = ni * 16 + c15;
                    #pragma unroll
                    for (int r = 0; r < 4; ++r) {
                        const int col = mi * 16 + (lane >> 4) * 4 + r;   // local co 0..63
                        ot[(col * TH + hh) * OT_STRIDE + wloc] =
                            acc[mi][ni][r] + bias_lds[p * 64 + col];
                    }
                }
            }
        }
        asm volatile("s_waitcnt lgkmcnt(0)" ::: "memory");
        __builtin_amdgcn_sched_barrier(0);
        __builtin_amdgcn_s_barrier();
        // 512 threads x 4 iters = 2048 float4 = 64co x 4h x 32w
        #pragma unroll
        for (int it = 0; it < 4; ++it) {
            const int col = it * 16 + (tid >> 5);    // local co 0..63
            const int hh  = (tid >> 3) & 3;
            const int w4  = (tid & 7) * 4;
            const float* src = &ot[(col * TH + hh) * OT_STRIDE + w4];
            f32x4 v = { src[0], src[1], src[2], src[3] };
            __builtin_nontemporal_store(v,
                (f32x4*)&out[(((size_t)b * COUT + p * 64 + col) * HH + h0 + hh) * WW + w0 + w4]);
        }
        if (p == 0) {
            asm volatile("s_waitcnt lgkmcnt(0)" ::: "memory");
            __builtin_amdgcn_sched_barrier(0);
            __builtin_amdgcn_s_barrier();     // ot reads done before p=1 overwrites
        }
    }
}

extern "C" void kernel_launch(void* const* d_in, const int* in_sizes, int n_in,
                              void* d_out, int out_size, void* d_ws, size_t ws_size,
                              hipStream_t stream) {
    const float* x    = (const float*)d_in[0];
    const float* k0   = (const float*)d_in[1];
    const float* k1   = (const float*)d_in[2];
    const float* bias = (const float*)d_in[3];
    float* out        = (float*)d_out;
    unsigned short* wsw = (unsigned short*)d_ws;   // 7*128*64*2 = 114688 B

    prep_weights<<<dim3(14, 1, 1), 512, 0, stream>>>(k0, k1, wsw);
    hexconv_mfma<<<dim3(4096, 1, 1), 512, 0, stream>>>(x, wsw, bias, out);
}